// Round 8
// baseline (1268.038 us; speedup 1.0000x reference)
//
#include <hip/hip_runtime.h>
#include <hip/hip_bf16.h>

#define LNUM 4
#define ENUM 12
#define CH 256
#define MLP 128
#define HW 196
#define BNUM 128
#define ROWLEN 14
#define MTOT (BNUM * HW)   // 25088 rows
#define BM 128
#define MAXTILE 208        // ceil(25088/128)=196 + up to 12 partial tiles

// packed per-layer weight plane offsets (ushort elements)
#define PK_WQ 0
#define PK_WK 786432
#define PK_WV 1572864
#define PK_WO 2359296
#define PK_W1 3145728
#define PK_W2 3538944
#define PK_TOTAL 3932160

using bf16x8 = __attribute__((ext_vector_type(8))) short;
using f32x4 = __attribute__((ext_vector_type(4))) float;

__device__ inline unsigned short f2bf(float v) {
  __hip_bfloat16 b = __float2bfloat16(v);   // RNE
  return *reinterpret_cast<unsigned short*>(&b);
}
__device__ inline float bf2f(unsigned short u) {
  union { unsigned int i; float f; } cv;
  cv.i = ((unsigned int)u) << 16;
  return cv.f;
}
__device__ inline void split_bf(float v, unsigned short& hi, unsigned short& lo) {
  hi = f2bf(v);
  lo = f2bf(v - bf2f(hi));
}
__device__ inline bf16x8 ld16(const unsigned short* p) {
  return *reinterpret_cast<const bf16x8*>(p);
}

// ---------------------------------------------------------------------------
// Transpose stem (B, C, HW) -> x (B, HW, C)
__global__ __launch_bounds__(256) void transpose_stem(const float* __restrict__ stem,
                                                      float* __restrict__ x) {
  __shared__ float tile[32][33];
  int b = blockIdx.z;
  int c0 = blockIdx.x * 32;
  int p0 = blockIdx.y * 32;
  int tx = threadIdx.x;
  int ty = threadIdx.y;
  for (int i = ty; i < 32; i += 8) {
    int c = c0 + i, p = p0 + tx;
    if (p < HW) tile[i][tx] = stem[(size_t)b * CH * HW + (size_t)c * HW + p];
  }
  __syncthreads();
  for (int i = ty; i < 32; i += 8) {
    int p = p0 + i, c = c0 + tx;
    if (p < HW) x[(size_t)b * HW * CH + (size_t)p * CH + c] = tile[tx][i];
  }
}

// ---------------------------------------------------------------------------
// Router: per-batch mean over HW, logits, softmax, argmax, weight
__global__ __launch_bounds__(256) void router_kernel(
    const float* __restrict__ x, const float* __restrict__ gate_w,
    const float* __restrict__ gate_b, float* __restrict__ probs_out,
    float* __restrict__ idx_out, float* __restrict__ weight,
    int* __restrict__ eidx, int li) {
  int b = blockIdx.x;
  int c = threadIdx.x;  // 256
  const float* xb = x + (size_t)b * HW * CH;
  float s = 0.f;
  for (int p = 0; p < HW; ++p) s += xb[(size_t)p * CH + c];
  __shared__ float r[CH];
  r[c] = s * (1.0f / (float)HW);
  __syncthreads();
  __shared__ float logits[ENUM];
  if (c < ENUM) {
    float acc = gate_b[li * ENUM + c];
    for (int k = 0; k < CH; ++k)
      acc += r[k] * gate_w[((size_t)li * CH + k) * ENUM + c];
    logits[c] = acc;
  }
  __syncthreads();
  if (c == 0) {
    float mx = logits[0]; int am = 0;
    for (int e = 1; e < ENUM; ++e) if (logits[e] > mx) { mx = logits[e]; am = e; }
    float pr[ENUM]; float den = 0.f;
    for (int e = 0; e < ENUM; ++e) { pr[e] = expf(logits[e] - mx); den += pr[e]; }
    float inv = 1.0f / den;
    for (int e = 0; e < ENUM; ++e) pr[e] *= inv;
    for (int e = 0; e < ENUM; ++e)
      probs_out[(size_t)(li * BNUM + b) * ENUM + e] = pr[e];
    idx_out[li * BNUM + b] = (float)am;
    float pmax = pr[am];
    weight[b] = pmax / (pmax + 1e-8f);
    eidx[b] = am;
  }
}

// ---------------------------------------------------------------------------
// Build batch permutation sorted by expert + GEMM tile table.
__global__ void route_plan(const int* __restrict__ eidx, int* __restrict__ perm,
                           int* __restrict__ tile_e, int* __restrict__ tile_row0,
                           int* __restrict__ tile_rows) {
  __shared__ int cnt[ENUM], start[ENUM];
  int t = threadIdx.x;  // 64
  if (t < ENUM) {
    int c = 0;
    for (int b = 0; b < BNUM; ++b) if (eidx[b] == t) ++c;
    cnt[t] = c;
  }
  __syncthreads();
  if (t == 0) {
    int s = 0;
    for (int e = 0; e < ENUM; ++e) { start[e] = s; s += cnt[e]; }
  }
  __syncthreads();
  if (t < ENUM) {
    int pos = start[t];
    for (int b = 0; b < BNUM; ++b) if (eidx[b] == t) perm[pos++] = b;
  }
  __syncthreads();
  if (t == 0) {
    int tile = 0;
    for (int e = 0; e < ENUM; ++e) {
      int rows = cnt[e] * HW;
      int row0 = start[e] * HW;
      int off = 0;
      while (off < rows) {
        tile_e[tile] = e;
        tile_row0[tile] = row0 + off;
        int rem = rows - off;
        tile_rows[tile] = rem < BM ? rem : BM;
        ++tile; off += BM;
      }
    }
    for (; tile < MAXTILE; ++tile) { tile_rows[tile] = 0; tile_e[tile] = 0; tile_row0[tile] = 0; }
  }
}

// ---------------------------------------------------------------------------
// Pre-split + pre-pack one layer's weights into MFMA B-fragment layout:
// dst[kg][n][8] bf16 hi/lo, per (tensor, expert). src ptrs are layer-offset.
__global__ __launch_bounds__(256) void prepack(
    const float* __restrict__ wq, const float* __restrict__ wk,
    const float* __restrict__ wv, const float* __restrict__ wo,
    const float* __restrict__ w1, const float* __restrict__ w2,
    unsigned short* __restrict__ Phi, unsigned short* __restrict__ Plo) {
  int e = blockIdx.z;     // 12
  int ts = blockIdx.y;    // 6
  int K = (ts == 5) ? 128 : 256;
  int N = (ts == 4) ? 128 : 256;
  int total = (K / 8) * N;
  int id = blockIdx.x * 256 + threadIdx.x;
  if (id >= total) return;
  const float* src;
  size_t dst0;
  switch (ts) {
    case 0: src = wq; dst0 = PK_WQ; break;
    case 1: src = wk; dst0 = PK_WK; break;
    case 2: src = wv; dst0 = PK_WV; break;
    case 3: src = wo; dst0 = PK_WO; break;
    case 4: src = w1; dst0 = PK_W1; break;
    default: src = w2; dst0 = PK_W2; break;
  }
  src += (size_t)e * K * N;
  dst0 += (size_t)e * K * N;
  int n = id % N;
  int kg = id / N;
  const float* sp = src + (size_t)kg * 8 * N + n;
  unsigned short hs[8], ls[8];
#pragma unroll
  for (int j = 0; j < 8; ++j) split_bf(sp[(size_t)j * N], hs[j], ls[j]);
  uint4 ph, pl;
  ph.x = hs[0] | ((unsigned)hs[1] << 16); ph.y = hs[2] | ((unsigned)hs[3] << 16);
  ph.z = hs[4] | ((unsigned)hs[5] << 16); ph.w = hs[6] | ((unsigned)hs[7] << 16);
  pl.x = ls[0] | ((unsigned)ls[1] << 16); pl.y = ls[2] | ((unsigned)ls[3] << 16);
  pl.z = ls[4] | ((unsigned)ls[5] << 16); pl.w = ls[6] | ((unsigned)ls[7] << 16);
  size_t o = dst0 + (size_t)(kg * N + n) * 8;
  *reinterpret_cast<uint4*>(Phi + o) = ph;
  *reinterpret_cast<uint4*>(Plo + o) = pl;
}

// ---------------------------------------------------------------------------
// LayerNorm: reads unsorted x via perm, writes sorted h as split bf16 (hi/lo).
__global__ __launch_bounds__(256) void ln_kernel(
    const float* __restrict__ xin, unsigned short* __restrict__ hhi,
    unsigned short* __restrict__ hlo,
    const float* __restrict__ g, const float* __restrict__ bta,
    const int* __restrict__ eidx, const int* __restrict__ perm, int li) {
  int t = blockIdx.x;          // sorted token id
  int s = t / HW, p = t - s * HW;
  int b = perm[s];
  int e = eidx[b];
  int c = threadIdx.x;
  float vx = xin[((size_t)b * HW + p) * CH + c];
  float sm = vx;
  for (int off = 32; off > 0; off >>= 1) sm += __shfl_down(sm, off, 64);
  __shared__ float wsum[4];
  __shared__ float red[2];
  int wid = c >> 6, lane = c & 63;
  if (lane == 0) wsum[wid] = sm;
  __syncthreads();
  if (c == 0) red[0] = (wsum[0] + wsum[1] + wsum[2] + wsum[3]) * (1.0f / (float)CH);
  __syncthreads();
  float mu = red[0];
  float d = vx - mu;
  float s2 = d * d;
  for (int off = 32; off > 0; off >>= 1) s2 += __shfl_down(s2, off, 64);
  if (lane == 0) wsum[wid] = s2;
  __syncthreads();
  if (c == 0) red[1] = (wsum[0] + wsum[1] + wsum[2] + wsum[3]) * (1.0f / (float)CH);
  __syncthreads();
  float rs = rsqrtf(red[1] + 1e-5f);
  size_t gb = ((size_t)li * ENUM + e) * CH + c;
  float hv = d * rs * g[gb] + bta[gb];
  unsigned short hi, lo;
  split_bf(hv, hi, lo);
  hhi[(size_t)t * CH + c] = hi;
  hlo[(size_t)t * CH + c] = lo;
}

// ---------------------------------------------------------------------------
// Split-bf16 MFMA grouped GEMM — LDS-free, barrier-free.
// A: planar hi/lo bf16, row-major stride KDIM. B: pre-packed [K/8][N][8] hi/lo.
// 512 threads = 8 waves (WR x WC), wave tile (128/WR) x (BN_/WC).
// EPI: 0 = QKV (cb selects tensor, fp32 store)
//      1 = GELU, split-bf16 store (stride MLP)
//      2 = residual add into unsorted X via perm
//      3 = (acc+bias+X)*wgt -> X and O0
template <int EPI, int BN_, int KDIM, int WR, int WC>
__global__ __launch_bounds__(512) void gemm_mfma(
    const unsigned short* __restrict__ Ahi, const unsigned short* __restrict__ Alo,
    const unsigned short* __restrict__ Whi, const unsigned short* __restrict__ Wlo,
    size_t wbase, size_t wstride,
    const float* __restrict__ B0, const float* __restrict__ B1p, const float* __restrict__ B2p,
    float* __restrict__ O0, float* __restrict__ O1p, float* __restrict__ O2p,
    unsigned short* __restrict__ Omhi, unsigned short* __restrict__ Omlo,
    float* __restrict__ X, const float* __restrict__ wgt,
    const int* __restrict__ tile_e, const int* __restrict__ tile_row0,
    const int* __restrict__ tile_rows, const int* __restrict__ perm, int li) {
  constexpr int FM = 128 / (WR * 16);
  constexpr int FN = BN_ / (WC * 16);
  int rows = tile_rows[blockIdx.y];
  if (rows <= 0) return;
  int row0 = tile_row0[blockIdx.y];
  int e = tile_e[blockIdx.y];
  int cb = blockIdx.x;

  const float* Bt = (EPI == 0) ? (cb == 0 ? B0 : (cb == 1 ? B1p : B2p)) : B0;
  float* Oo = (EPI == 0) ? (cb == 0 ? O0 : (cb == 1 ? O1p : O2p)) : O0;
  size_t woff = wbase + (size_t)cb * wstride + (size_t)e * (KDIM * BN_);
  const unsigned short* Wh = Whi + woff;
  const unsigned short* Wl = Wlo + woff;
  const float* bias = Bt + ((size_t)li * ENUM + e) * BN_;

  int tid = threadIdx.x;
  int lane = tid & 63, wid = tid >> 6;
  int wr = wid / WC, wc = wid % WC;
  int r0w = wr * (128 / WR), c0w = wc * (BN_ / WC);
  int lrow = lane & 15, lk = lane >> 4;

  // A fragment row pointers (clamped to tile for partial tiles)
  const unsigned short* aH[FM];
  const unsigned short* aL[FM];
#pragma unroll
  for (int fi = 0; fi < FM; ++fi) {
    int rl = r0w + fi * 16 + lrow;
    if (rl >= rows) rl = 0;
    size_t ro = (size_t)(row0 + rl) * KDIM + lk * 8;
    aH[fi] = Ahi + ro;
    aL[fi] = Alo + ro;
  }
  int colj[FN];
#pragma unroll
  for (int fj = 0; fj < FN; ++fj) colj[fj] = c0w + fj * 16 + lrow;

  f32x4 acc[FM][FN];
#pragma unroll
  for (int i = 0; i < FM; ++i)
#pragma unroll
    for (int j = 0; j < FN; ++j) acc[i][j] = (f32x4){0.f, 0.f, 0.f, 0.f};

#pragma unroll
  for (int t = 0; t < KDIM / 32; ++t) {
    bf16x8 ah[FM], al[FM], bh[FN], bl[FN];
#pragma unroll
    for (int fi = 0; fi < FM; ++fi) {
      ah[fi] = ld16(aH[fi] + t * 32);
      al[fi] = ld16(aL[fi] + t * 32);
    }
#pragma unroll
    for (int fj = 0; fj < FN; ++fj) {
      size_t bo = ((size_t)(t * 4 + lk) * BN_ + colj[fj]) * 8;
      bh[fj] = ld16(Wh + bo);
      bl[fj] = ld16(Wl + bo);
    }
#pragma unroll
    for (int fi = 0; fi < FM; ++fi)
#pragma unroll
      for (int fj = 0; fj < FN; ++fj) {
        acc[fi][fj] = __builtin_amdgcn_mfma_f32_16x16x32_bf16(ah[fi], bh[fj], acc[fi][fj], 0, 0, 0);
        acc[fi][fj] = __builtin_amdgcn_mfma_f32_16x16x32_bf16(ah[fi], bl[fj], acc[fi][fj], 0, 0, 0);
        acc[fi][fj] = __builtin_amdgcn_mfma_f32_16x16x32_bf16(al[fi], bh[fj], acc[fi][fj], 0, 0, 0);
      }
  }

  // ---- epilogue
#pragma unroll
  for (int fi = 0; fi < FM; ++fi) {
#pragma unroll
    for (int r = 0; r < 4; ++r) {
      int row_l = r0w + fi * 16 + lk * 4 + r;
      if (row_l >= rows) continue;
      int rg = row0 + row_l;
      int bsrt = 0; size_t gxb = 0; float wr_ = 1.f;
      if (EPI >= 2) {
        int s = rg / HW, p = rg - s * HW;
        bsrt = perm[s];
        gxb = ((size_t)bsrt * HW + p) * CH;
        if (EPI == 3) wr_ = wgt[bsrt];
      }
#pragma unroll
      for (int fj = 0; fj < FN; ++fj) {
        int col = c0w + fj * 16 + lrow;
        float v = acc[fi][fj][r] + bias[col];
        if (EPI == 0) {
          Oo[(size_t)rg * BN_ + col] = v;
        } else if (EPI == 1) {
          float gl = 0.5f * v * (1.0f + erff(v * 0.70710678118654752f));
          unsigned short hi, lo;
          split_bf(gl, hi, lo);
          Omhi[(size_t)rg * MLP + col] = hi;
          Omlo[(size_t)rg * MLP + col] = lo;
        } else if (EPI == 2) {
          X[gxb + col] += v;
        } else {
          float vv = (v + X[gxb + col]) * wr_;
          X[gxb + col] = vv;
          O0[gxb + col] = vv;
        }
      }
    }
  }
}

// ---------------------------------------------------------------------------
// Row-local attention on sorted fp32 q/k/v; writes split-bf16 o into h buffers.
__global__ __launch_bounds__(256) void attn_kernel(
    const float* __restrict__ q, const float* __restrict__ k,
    const float* __restrict__ v, unsigned short* __restrict__ ohi,
    unsigned short* __restrict__ olo) {
  int br = blockIdx.x;  // sorted_batch*14 + row
  int b = br / ROWLEN, row = br % ROWLEN;
  size_t base = ((size_t)b * HW + (size_t)row * ROWLEN) * CH;
  __shared__ float qs[ROWLEN][CH + 1];
  __shared__ float ks[ROWLEN][CH + 1];
  __shared__ float vs[ROWLEN][CH + 1];
  __shared__ float sc[4][ROWLEN][ROWLEN];
  int tid = threadIdx.x;  // 256
  for (int w = 0; w < ROWLEN; ++w) {
    qs[w][tid] = q[base + (size_t)w * CH + tid];
    ks[w][tid] = k[base + (size_t)w * CH + tid];
    vs[w][tid] = v[base + (size_t)w * CH + tid];
  }
  __syncthreads();
  for (int sidx = tid; sidx < 4 * ROWLEN * ROWLEN; sidx += 256) {
    int n = sidx / (ROWLEN * ROWLEN);
    int rem = sidx % (ROWLEN * ROWLEN);
    int i = rem / ROWLEN, j = rem % ROWLEN;
    const float* qp = &qs[i][n * 64];
    const float* kp = &ks[j][n * 64];
    float s = 0.f;
#pragma unroll
    for (int d = 0; d < 64; ++d) s = fmaf(qp[d], kp[d], s);
    sc[n][i][j] = s * 0.125f;
  }
  __syncthreads();
  if (tid < 4 * ROWLEN) {
    int n = tid / ROWLEN, i = tid % ROWLEN;
    float mx = sc[n][i][0];
    for (int j = 1; j < ROWLEN; ++j) mx = fmaxf(mx, sc[n][i][j]);
    float ex[ROWLEN]; float den = 0.f;
    for (int j = 0; j < ROWLEN; ++j) { ex[j] = expf(sc[n][i][j] - mx); den += ex[j]; }
    float inv = 1.0f / den;
    for (int j = 0; j < ROWLEN; ++j) sc[n][i][j] = ex[j] * inv;
  }
  __syncthreads();
  int n = tid / 64;
  for (int i = 0; i < ROWLEN; ++i) {
    float s = 0.f;
#pragma unroll
    for (int j = 0; j < ROWLEN; ++j) s = fmaf(sc[n][i][j], vs[j][tid], s);
    unsigned short hi, lo;
    split_bf(s, hi, lo);
    ohi[base + (size_t)i * CH + tid] = hi;
    olo[base + (size_t)i * CH + tid] = lo;
  }
}

// ---------------------------------------------------------------------------
extern "C" void kernel_launch(void* const* d_in, const int* in_sizes, int n_in,
                              void* d_out, int out_size, void* d_ws, size_t ws_size,
                              hipStream_t stream) {
  const float* stem = (const float*)d_in[0];
  const float* gate_w = (const float*)d_in[1];
  const float* gate_b = (const float*)d_in[2];
  const float* ln1_g = (const float*)d_in[3];
  const float* ln1_b = (const float*)d_in[4];
  const float* wq = (const float*)d_in[5];
  const float* bq = (const float*)d_in[6];
  const float* wk = (const float*)d_in[7];
  const float* bk = (const float*)d_in[8];
  const float* wv = (const float*)d_in[9];
  const float* bv = (const float*)d_in[10];
  const float* wo = (const float*)d_in[11];
  const float* bo = (const float*)d_in[12];
  const float* ln2_g = (const float*)d_in[13];
  const float* ln2_b = (const float*)d_in[14];
  const float* w1 = (const float*)d_in[15];
  const float* b1 = (const float*)d_in[16];
  const float* w2 = (const float*)d_in[17];
  const float* b2 = (const float*)d_in[18];

  float* out = (float*)d_out;
  float* ws = (float*)d_ws;
  const size_t IMG = (size_t)BNUM * HW * CH;  // 6,422,528 floats
  float* x = ws;                                       // fp32 residual
  unsigned short* h_hi = (unsigned short*)(ws + IMG);  // MTOT*CH ushorts
  unsigned short* h_lo = h_hi + (size_t)MTOT * CH;
  float* q = ws + 2 * IMG;
  float* k = ws + 3 * IMG;
  float* v = ws + 4 * IMG;
  unsigned short* m_hi = (unsigned short*)q;  // alias: q dead after attn
  unsigned short* m_lo = m_hi + (size_t)MTOT * MLP;
  unsigned short* Whi_p = (unsigned short*)(ws + 5 * IMG);
  unsigned short* Wlo_p = Whi_p + PK_TOTAL;
  float* weight = ws + 5 * IMG + PK_TOTAL;  // PK_TOTAL ushorts*2 = PK_TOTAL floats
  int* eidx = (int*)(weight + BNUM);
  int* perm = eidx + BNUM;
  int* tile_e = perm + BNUM;
  int* tile_row0 = tile_e + MAXTILE;
  int* tile_rows = tile_row0 + MAXTILE;

  float* probs_out = out + 4 * IMG;
  float* idx_out = probs_out + (size_t)LNUM * BNUM * ENUM;

  transpose_stem<<<dim3(8, 7, BNUM), dim3(32, 8), 0, stream>>>(stem, x);

  for (int li = 0; li < LNUM; ++li) {
    router_kernel<<<BNUM, 256, 0, stream>>>(x, gate_w, gate_b, probs_out, idx_out,
                                            weight, eidx, li);
    route_plan<<<1, 64, 0, stream>>>(eidx, perm, tile_e, tile_row0, tile_rows);
    prepack<<<dim3(32, 6, ENUM), 256, 0, stream>>>(
        wq + (size_t)li * ENUM * CH * CH, wk + (size_t)li * ENUM * CH * CH,
        wv + (size_t)li * ENUM * CH * CH, wo + (size_t)li * ENUM * CH * CH,
        w1 + (size_t)li * ENUM * CH * MLP, w2 + (size_t)li * ENUM * MLP * CH,
        Whi_p, Wlo_p);
    ln_kernel<<<MTOT, 256, 0, stream>>>(x, h_hi, h_lo, ln1_g, ln1_b, eidx, perm, li);
    gemm_mfma<0, 256, 256, 2, 4><<<dim3(3, MAXTILE), 512, 0, stream>>>(
        h_hi, h_lo, Whi_p, Wlo_p, PK_WQ, (size_t)(ENUM * CH * CH),
        bq, bk, bv, q, k, v, nullptr, nullptr, nullptr, nullptr,
        tile_e, tile_row0, tile_rows, perm, li);
    attn_kernel<<<BNUM * ROWLEN, 256, 0, stream>>>(q, k, v, h_hi, h_lo);
    gemm_mfma<2, 256, 256, 2, 4><<<dim3(1, MAXTILE), 512, 0, stream>>>(
        h_hi, h_lo, Whi_p, Wlo_p, PK_WO, 0,
        bo, nullptr, nullptr, nullptr, nullptr, nullptr, nullptr, nullptr,
        x, nullptr, tile_e, tile_row0, tile_rows, perm, li);
    ln_kernel<<<MTOT, 256, 0, stream>>>(x, h_hi, h_lo, ln2_g, ln2_b, eidx, perm, li);
    gemm_mfma<1, 128, 256, 2, 4><<<dim3(1, MAXTILE), 512, 0, stream>>>(
        h_hi, h_lo, Whi_p, Wlo_p, PK_W1, 0,
        b1, nullptr, nullptr, nullptr, nullptr, nullptr, m_hi, m_lo,
        nullptr, nullptr, tile_e, tile_row0, tile_rows, perm, li);
    gemm_mfma<3, 256, 128, 2, 4><<<dim3(1, MAXTILE), 512, 0, stream>>>(
        m_hi, m_lo, Whi_p, Wlo_p, PK_W2, 0,
        b2, nullptr, nullptr, out + (size_t)li * IMG, nullptr, nullptr,
        nullptr, nullptr, x, weight, tile_e, tile_row0, tile_rows, perm, li);
  }
}

// Round 9
// 1038.786 us; speedup vs baseline: 1.2207x; 1.2207x over previous
//
#include <hip/hip_runtime.h>
#include <hip/hip_bf16.h>

#define LNUM 4
#define ENUM 12
#define CH 256
#define MLP 128
#define HW 196
#define BNUM 128
#define ROWLEN 14
#define MTOT (BNUM * HW)   // 25088 rows
#define TM 64              // GEMM row-tile
#define MAXTILE 416        // 25088/64=392 full + <=12 partial

// packed per-layer weight plane offsets (ushort elements)
#define PK_WQ 0
#define PK_WK 786432
#define PK_WV 1572864
#define PK_WO 2359296
#define PK_W1 3145728
#define PK_W2 3538944
#define PK_TOTAL 3932160

using bf16x8 = __attribute__((ext_vector_type(8))) short;
using f32x4 = __attribute__((ext_vector_type(4))) float;

__device__ inline unsigned short f2bf(float v) {
  __hip_bfloat16 b = __float2bfloat16(v);   // RNE
  return *reinterpret_cast<unsigned short*>(&b);
}
__device__ inline float bf2f(unsigned short u) {
  union { unsigned int i; float f; } cv;
  cv.i = ((unsigned int)u) << 16;
  return cv.f;
}
__device__ inline void split_bf(float v, unsigned short& hi, unsigned short& lo) {
  hi = f2bf(v);
  lo = f2bf(v - bf2f(hi));
}
// async global->LDS 16B per lane; dest = uniform base + lane*16
__device__ inline void gload16(const void* g, void* l) {
  __builtin_amdgcn_global_load_lds(
      (const __attribute__((address_space(1))) unsigned int*)g,
      (__attribute__((address_space(3))) unsigned int*)l, 16, 0, 0);
}

// ---------------------------------------------------------------------------
__global__ __launch_bounds__(256) void transpose_stem(const float* __restrict__ stem,
                                                      float* __restrict__ x) {
  __shared__ float tile[32][33];
  int b = blockIdx.z;
  int c0 = blockIdx.x * 32;
  int p0 = blockIdx.y * 32;
  int tx = threadIdx.x;
  int ty = threadIdx.y;
  for (int i = ty; i < 32; i += 8) {
    int c = c0 + i, p = p0 + tx;
    if (p < HW) tile[i][tx] = stem[(size_t)b * CH * HW + (size_t)c * HW + p];
  }
  __syncthreads();
  for (int i = ty; i < 32; i += 8) {
    int p = p0 + i, c = c0 + tx;
    if (p < HW) x[(size_t)b * HW * CH + (size_t)p * CH + c] = tile[tx][i];
  }
}

// ---------------------------------------------------------------------------
__global__ __launch_bounds__(256) void router_kernel(
    const float* __restrict__ x, const float* __restrict__ gate_w,
    const float* __restrict__ gate_b, float* __restrict__ probs_out,
    float* __restrict__ idx_out, float* __restrict__ weight,
    int* __restrict__ eidx, int li) {
  int b = blockIdx.x;
  int c = threadIdx.x;  // 256
  const float* xb = x + (size_t)b * HW * CH;
  float s = 0.f;
  for (int p = 0; p < HW; ++p) s += xb[(size_t)p * CH + c];
  __shared__ float r[CH];
  r[c] = s * (1.0f / (float)HW);
  __syncthreads();
  __shared__ float logits[ENUM];
  if (c < ENUM) {
    float acc = gate_b[li * ENUM + c];
    for (int k = 0; k < CH; ++k)
      acc += r[k] * gate_w[((size_t)li * CH + k) * ENUM + c];
    logits[c] = acc;
  }
  __syncthreads();
  if (c == 0) {
    float mx = logits[0]; int am = 0;
    for (int e = 1; e < ENUM; ++e) if (logits[e] > mx) { mx = logits[e]; am = e; }
    float pr[ENUM]; float den = 0.f;
    for (int e = 0; e < ENUM; ++e) { pr[e] = expf(logits[e] - mx); den += pr[e]; }
    float inv = 1.0f / den;
    for (int e = 0; e < ENUM; ++e) pr[e] *= inv;
    for (int e = 0; e < ENUM; ++e)
      probs_out[(size_t)(li * BNUM + b) * ENUM + e] = pr[e];
    idx_out[li * BNUM + b] = (float)am;
    float pmax = pr[am];
    weight[b] = pmax / (pmax + 1e-8f);
    eidx[b] = am;
  }
}

// ---------------------------------------------------------------------------
__global__ void route_plan(const int* __restrict__ eidx, int* __restrict__ perm,
                           int* __restrict__ tile_e, int* __restrict__ tile_row0,
                           int* __restrict__ tile_rows) {
  __shared__ int cnt[ENUM], start[ENUM];
  int t = threadIdx.x;  // 64
  if (t < ENUM) {
    int c = 0;
    for (int b = 0; b < BNUM; ++b) if (eidx[b] == t) ++c;
    cnt[t] = c;
  }
  __syncthreads();
  if (t == 0) {
    int s = 0;
    for (int e = 0; e < ENUM; ++e) { start[e] = s; s += cnt[e]; }
  }
  __syncthreads();
  if (t < ENUM) {
    int pos = start[t];
    for (int b = 0; b < BNUM; ++b) if (eidx[b] == t) perm[pos++] = b;
  }
  __syncthreads();
  if (t == 0) {
    int tile = 0;
    for (int e = 0; e < ENUM; ++e) {
      int rows = cnt[e] * HW;
      int row0 = start[e] * HW;
      int off = 0;
      while (off < rows) {
        tile_e[tile] = e;
        tile_row0[tile] = row0 + off;
        int rem = rows - off;
        tile_rows[tile] = rem < TM ? rem : TM;
        ++tile; off += TM;
      }
    }
    for (; tile < MAXTILE; ++tile) { tile_rows[tile] = 0; tile_e[tile] = 0; tile_row0[tile] = 0; }
  }
}

// ---------------------------------------------------------------------------
// Pre-split + pre-pack one layer's weights: [K/8][N][8] bf16 hi/lo per expert.
__global__ __launch_bounds__(256) void prepack(
    const float* __restrict__ wq, const float* __restrict__ wk,
    const float* __restrict__ wv, const float* __restrict__ wo,
    const float* __restrict__ w1, const float* __restrict__ w2,
    unsigned short* __restrict__ Phi, unsigned short* __restrict__ Plo) {
  int e = blockIdx.z;     // 12
  int ts = blockIdx.y;    // 6
  int K = (ts == 5) ? 128 : 256;
  int N = (ts == 4) ? 128 : 256;
  int total = (K / 8) * N;
  int id = blockIdx.x * 256 + threadIdx.x;
  if (id >= total) return;
  const float* src;
  size_t dst0;
  switch (ts) {
    case 0: src = wq; dst0 = PK_WQ; break;
    case 1: src = wk; dst0 = PK_WK; break;
    case 2: src = wv; dst0 = PK_WV; break;
    case 3: src = wo; dst0 = PK_WO; break;
    case 4: src = w1; dst0 = PK_W1; break;
    default: src = w2; dst0 = PK_W2; break;
  }
  src += (size_t)e * K * N;
  dst0 += (size_t)e * K * N;
  int n = id % N;
  int kg = id / N;
  const float* sp = src + (size_t)kg * 8 * N + n;
  unsigned short hs[8], ls[8];
#pragma unroll
  for (int j = 0; j < 8; ++j) split_bf(sp[(size_t)j * N], hs[j], ls[j]);
  uint4 ph, pl;
  ph.x = hs[0] | ((unsigned)hs[1] << 16); ph.y = hs[2] | ((unsigned)hs[3] << 16);
  ph.z = hs[4] | ((unsigned)hs[5] << 16); ph.w = hs[6] | ((unsigned)hs[7] << 16);
  pl.x = ls[0] | ((unsigned)ls[1] << 16); pl.y = ls[2] | ((unsigned)ls[3] << 16);
  pl.z = ls[4] | ((unsigned)ls[5] << 16); pl.w = ls[6] | ((unsigned)ls[7] << 16);
  size_t o = dst0 + (size_t)(kg * N + n) * 8;
  *reinterpret_cast<uint4*>(Phi + o) = ph;
  *reinterpret_cast<uint4*>(Plo + o) = pl;
}

// ---------------------------------------------------------------------------
__global__ __launch_bounds__(256) void ln_kernel(
    const float* __restrict__ xin, unsigned short* __restrict__ hhi,
    unsigned short* __restrict__ hlo,
    const float* __restrict__ g, const float* __restrict__ bta,
    const int* __restrict__ eidx, const int* __restrict__ perm, int li) {
  int t = blockIdx.x;          // sorted token id
  int s = t / HW, p = t - s * HW;
  int b = perm[s];
  int e = eidx[b];
  int c = threadIdx.x;
  float vx = xin[((size_t)b * HW + p) * CH + c];
  float sm = vx;
  for (int off = 32; off > 0; off >>= 1) sm += __shfl_down(sm, off, 64);
  __shared__ float wsum[4];
  __shared__ float red[2];
  int wid = c >> 6, lane = c & 63;
  if (lane == 0) wsum[wid] = sm;
  __syncthreads();
  if (c == 0) red[0] = (wsum[0] + wsum[1] + wsum[2] + wsum[3]) * (1.0f / (float)CH);
  __syncthreads();
  float mu = red[0];
  float d = vx - mu;
  float s2 = d * d;
  for (int off = 32; off > 0; off >>= 1) s2 += __shfl_down(s2, off, 64);
  if (lane == 0) wsum[wid] = s2;
  __syncthreads();
  if (c == 0) red[1] = (wsum[0] + wsum[1] + wsum[2] + wsum[3]) * (1.0f / (float)CH);
  __syncthreads();
  float rs = rsqrtf(red[1] + 1e-5f);
  size_t gb = ((size_t)li * ENUM + e) * CH + c;
  float hv = d * rs * g[gb] + bta[gb];
  unsigned short hi, lo;
  split_bf(hv, hi, lo);
  hhi[(size_t)t * CH + c] = hi;
  hlo[(size_t)t * CH + c] = lo;
}

// ---------------------------------------------------------------------------
// Split-bf16 MFMA grouped GEMM with async LDS staging (global_load_lds w=16).
// Tile 64x128, BK=32, 256 thr = 4 waves (2x2), wave tile 32x64.
// A: planar hi/lo bf16 stride KDIM. B: prepacked [K/8][N][8] hi/lo.
// EPI: 0 QKV fp32 store | 1 GELU split-bf16 store | 2 +X via perm | 3 (.+X)*w dual
template <int EPI, int NT, int KDIM>
__global__ __launch_bounds__(256) void gemm_mfma(
    const unsigned short* __restrict__ Ahi, const unsigned short* __restrict__ Alo,
    const unsigned short* __restrict__ Whi, const unsigned short* __restrict__ Wlo,
    size_t wbase, size_t wstride,
    const float* __restrict__ B0, const float* __restrict__ B1p, const float* __restrict__ B2p,
    float* __restrict__ O0, float* __restrict__ O1p, float* __restrict__ O2p,
    unsigned short* __restrict__ Omhi, unsigned short* __restrict__ Omlo,
    float* __restrict__ X, const float* __restrict__ wgt,
    const int* __restrict__ tile_e, const int* __restrict__ tile_row0,
    const int* __restrict__ tile_rows, const int* __restrict__ perm, int li) {
  constexpr int NX = NT / 128;   // n-tiles per tensor
  int rows = tile_rows[blockIdx.y];
  if (rows <= 0) return;
  int row0 = tile_row0[blockIdx.y];
  int e = tile_e[blockIdx.y];
  int cb = blockIdx.x / NX;
  int ncol0 = (blockIdx.x % NX) * 128;

  const float* Bt = (EPI == 0) ? (cb == 0 ? B0 : (cb == 1 ? B1p : B2p)) : B0;
  float* Oo = (EPI == 0) ? (cb == 0 ? O0 : (cb == 1 ? O1p : O2p)) : O0;
  size_t woff = wbase + (size_t)cb * wstride + (size_t)e * (KDIM * NT);
  const unsigned short* Wh = Whi + woff;
  const unsigned short* Wl = Wlo + woff;
  const float* bias = Bt + ((size_t)li * ENUM + e) * NT + ncol0;

  __shared__ unsigned short Ash[4][TM][8], Asl[4][TM][8];
  __shared__ unsigned short Bsh[4][128][8], Bsl[4][128][8];

  int tid = threadIdx.x;
  int lane = tid & 63, w = tid >> 6;     // wave id 0..3 doubles as kg
  int wr = w >> 1, wc = w & 1;
  int r0w = wr * 32, c0w = wc * 64;
  int lrow = lane & 15, lk = lane >> 4;

  // staging source pointers (per-lane global, wave-uniform LDS base)
  int arow = row0 + (lane < rows ? lane : 0);
  const unsigned short* gAh = Ahi + (size_t)arow * KDIM + w * 8;
  const unsigned short* gAl = Alo + (size_t)arow * KDIM + w * 8;

  f32x4 acc[2][4];
#pragma unroll
  for (int i = 0; i < 2; ++i)
#pragma unroll
    for (int j = 0; j < 4; ++j) acc[i][j] = (f32x4){0.f, 0.f, 0.f, 0.f};

#pragma unroll
  for (int t = 0; t < KDIM / 32; ++t) {
    int k0 = t * 32;
    gload16(gAh + k0, &Ash[w][0][0]);
    gload16(gAl + k0, &Asl[w][0][0]);
    const unsigned short* gBh = Wh + ((size_t)(t * 4 + w) * NT + ncol0 + lane) * 8;
    const unsigned short* gBl = Wl + ((size_t)(t * 4 + w) * NT + ncol0 + lane) * 8;
    gload16(gBh, &Bsh[w][0][0]);
    gload16(gBh + 64 * 8, &Bsh[w][64][0]);
    gload16(gBl, &Bsl[w][0][0]);
    gload16(gBl + 64 * 8, &Bsl[w][64][0]);
    __syncthreads();   // drains vmcnt (compiler emits waitcnt before barrier)
    bf16x8 ah[2], al[2], bh[4], bl[4];
#pragma unroll
    for (int fi = 0; fi < 2; ++fi) {
      ah[fi] = *reinterpret_cast<const bf16x8*>(&Ash[lk][r0w + fi * 16 + lrow][0]);
      al[fi] = *reinterpret_cast<const bf16x8*>(&Asl[lk][r0w + fi * 16 + lrow][0]);
    }
#pragma unroll
    for (int fj = 0; fj < 4; ++fj) {
      bh[fj] = *reinterpret_cast<const bf16x8*>(&Bsh[lk][c0w + fj * 16 + lrow][0]);
      bl[fj] = *reinterpret_cast<const bf16x8*>(&Bsl[lk][c0w + fj * 16 + lrow][0]);
    }
#pragma unroll
    for (int fi = 0; fi < 2; ++fi)
#pragma unroll
      for (int fj = 0; fj < 4; ++fj) {
        acc[fi][fj] = __builtin_amdgcn_mfma_f32_16x16x32_bf16(ah[fi], bh[fj], acc[fi][fj], 0, 0, 0);
        acc[fi][fj] = __builtin_amdgcn_mfma_f32_16x16x32_bf16(ah[fi], bl[fj], acc[fi][fj], 0, 0, 0);
        acc[fi][fj] = __builtin_amdgcn_mfma_f32_16x16x32_bf16(al[fi], bh[fj], acc[fi][fj], 0, 0, 0);
      }
    __syncthreads();   // protect LDS before next stage overwrites
  }

  // ---- epilogue
#pragma unroll
  for (int fi = 0; fi < 2; ++fi) {
#pragma unroll
    for (int r = 0; r < 4; ++r) {
      int row_l = r0w + fi * 16 + lk * 4 + r;
      if (row_l >= rows) continue;
      int rg = row0 + row_l;
      int bsrt = 0; size_t gxb = 0; float wr_ = 1.f;
      if (EPI >= 2) {
        int s = rg / HW, p = rg - s * HW;
        bsrt = perm[s];
        gxb = ((size_t)bsrt * HW + p) * CH;
        if (EPI == 3) wr_ = wgt[bsrt];
      }
#pragma unroll
      for (int fj = 0; fj < 4; ++fj) {
        int col = c0w + fj * 16 + lrow;       // within this 128-tile
        int ocol = ncol0 + col;               // within tensor
        float v = acc[fi][fj][r] + bias[col];
        if (EPI == 0) {
          Oo[(size_t)rg * NT + ocol] = v;
        } else if (EPI == 1) {
          float gl = 0.5f * v * (1.0f + erff(v * 0.70710678118654752f));
          unsigned short hi, lo;
          split_bf(gl, hi, lo);
          Omhi[(size_t)rg * MLP + ocol] = hi;
          Omlo[(size_t)rg * MLP + ocol] = lo;
        } else if (EPI == 2) {
          X[gxb + ocol] += v;
        } else {
          float vv = (v + X[gxb + ocol]) * wr_;
          X[gxb + ocol] = vv;
          O0[gxb + ocol] = vv;
        }
      }
    }
  }
}

// ---------------------------------------------------------------------------
__global__ __launch_bounds__(256) void attn_kernel(
    const float* __restrict__ q, const float* __restrict__ k,
    const float* __restrict__ v, unsigned short* __restrict__ ohi,
    unsigned short* __restrict__ olo) {
  int br = blockIdx.x;  // sorted_batch*14 + row
  int b = br / ROWLEN, row = br % ROWLEN;
  size_t base = ((size_t)b * HW + (size_t)row * ROWLEN) * CH;
  __shared__ float qs[ROWLEN][CH + 1];
  __shared__ float ks[ROWLEN][CH + 1];
  __shared__ float vs[ROWLEN][CH + 1];
  __shared__ float sc[4][ROWLEN][ROWLEN];
  int tid = threadIdx.x;  // 256
  for (int w = 0; w < ROWLEN; ++w) {
    qs[w][tid] = q[base + (size_t)w * CH + tid];
    ks[w][tid] = k[base + (size_t)w * CH + tid];
    vs[w][tid] = v[base + (size_t)w * CH + tid];
  }
  __syncthreads();
  for (int sidx = tid; sidx < 4 * ROWLEN * ROWLEN; sidx += 256) {
    int n = sidx / (ROWLEN * ROWLEN);
    int rem = sidx % (ROWLEN * ROWLEN);
    int i = rem / ROWLEN, j = rem % ROWLEN;
    const float* qp = &qs[i][n * 64];
    const float* kp = &ks[j][n * 64];
    float s = 0.f;
#pragma unroll
    for (int d = 0; d < 64; ++d) s = fmaf(qp[d], kp[d], s);
    sc[n][i][j] = s * 0.125f;
  }
  __syncthreads();
  if (tid < 4 * ROWLEN) {
    int n = tid / ROWLEN, i = tid % ROWLEN;
    float mx = sc[n][i][0];
    for (int j = 1; j < ROWLEN; ++j) mx = fmaxf(mx, sc[n][i][j]);
    float ex[ROWLEN]; float den = 0.f;
    for (int j = 0; j < ROWLEN; ++j) { ex[j] = expf(sc[n][i][j] - mx); den += ex[j]; }
    float inv = 1.0f / den;
    for (int j = 0; j < ROWLEN; ++j) sc[n][i][j] = ex[j] * inv;
  }
  __syncthreads();
  int n = tid / 64;
  for (int i = 0; i < ROWLEN; ++i) {
    float s = 0.f;
#pragma unroll
    for (int j = 0; j < ROWLEN; ++j) s = fmaf(sc[n][i][j], vs[j][tid], s);
    unsigned short hi, lo;
    split_bf(s, hi, lo);
    ohi[base + (size_t)i * CH + tid] = hi;
    olo[base + (size_t)i * CH + tid] = lo;
  }
}

// ---------------------------------------------------------------------------
extern "C" void kernel_launch(void* const* d_in, const int* in_sizes, int n_in,
                              void* d_out, int out_size, void* d_ws, size_t ws_size,
                              hipStream_t stream) {
  const float* stem = (const float*)d_in[0];
  const float* gate_w = (const float*)d_in[1];
  const float* gate_b = (const float*)d_in[2];
  const float* ln1_g = (const float*)d_in[3];
  const float* ln1_b = (const float*)d_in[4];
  const float* wq = (const float*)d_in[5];
  const float* bq = (const float*)d_in[6];
  const float* wk = (const float*)d_in[7];
  const float* bk = (const float*)d_in[8];
  const float* wv = (const float*)d_in[9];
  const float* bv = (const float*)d_in[10];
  const float* wo = (const float*)d_in[11];
  const float* bo = (const float*)d_in[12];
  const float* ln2_g = (const float*)d_in[13];
  const float* ln2_b = (const float*)d_in[14];
  const float* w1 = (const float*)d_in[15];
  const float* b1 = (const float*)d_in[16];
  const float* w2 = (const float*)d_in[17];
  const float* b2 = (const float*)d_in[18];

  float* out = (float*)d_out;
  float* ws = (float*)d_ws;
  const size_t IMG = (size_t)BNUM * HW * CH;  // 6,422,528 floats
  float* x = ws;                                       // fp32 residual
  unsigned short* h_hi = (unsigned short*)(ws + IMG);
  unsigned short* h_lo = h_hi + (size_t)MTOT * CH;
  float* q = ws + 2 * IMG;
  float* k = ws + 3 * IMG;
  float* v = ws + 4 * IMG;
  unsigned short* m_hi = (unsigned short*)q;  // alias: q dead after attn
  unsigned short* m_lo = m_hi + (size_t)MTOT * MLP;
  unsigned short* Whi_p = (unsigned short*)(ws + 5 * IMG);
  unsigned short* Wlo_p = Whi_p + PK_TOTAL;
  float* weight = ws + 5 * IMG + PK_TOTAL;
  int* eidx = (int*)(weight + BNUM);
  int* perm = eidx + BNUM;
  int* tile_e = perm + BNUM;
  int* tile_row0 = tile_e + MAXTILE;
  int* tile_rows = tile_row0 + MAXTILE;

  float* probs_out = out + 4 * IMG;
  float* idx_out = probs_out + (size_t)LNUM * BNUM * ENUM;

  transpose_stem<<<dim3(8, 7, BNUM), dim3(32, 8), 0, stream>>>(stem, x);

  for (int li = 0; li < LNUM; ++li) {
    router_kernel<<<BNUM, 256, 0, stream>>>(x, gate_w, gate_b, probs_out, idx_out,
                                            weight, eidx, li);
    route_plan<<<1, 64, 0, stream>>>(eidx, perm, tile_e, tile_row0, tile_rows);
    prepack<<<dim3(32, 6, ENUM), 256, 0, stream>>>(
        wq + (size_t)li * ENUM * CH * CH, wk + (size_t)li * ENUM * CH * CH,
        wv + (size_t)li * ENUM * CH * CH, wo + (size_t)li * ENUM * CH * CH,
        w1 + (size_t)li * ENUM * CH * MLP, w2 + (size_t)li * ENUM * MLP * CH,
        Whi_p, Wlo_p);
    ln_kernel<<<MTOT, 256, 0, stream>>>(x, h_hi, h_lo, ln1_g, ln1_b, eidx, perm, li);
    gemm_mfma<0, 256, 256><<<dim3(6, MAXTILE), 256, 0, stream>>>(
        h_hi, h_lo, Whi_p, Wlo_p, PK_WQ, (size_t)(ENUM * CH * CH),
        bq, bk, bv, q, k, v, nullptr, nullptr, nullptr, nullptr,
        tile_e, tile_row0, tile_rows, perm, li);
    attn_kernel<<<BNUM * ROWLEN, 256, 0, stream>>>(q, k, v, h_hi, h_lo);
    gemm_mfma<2, 256, 256><<<dim3(2, MAXTILE), 256, 0, stream>>>(
        h_hi, h_lo, Whi_p, Wlo_p, PK_WO, 0,
        bo, nullptr, nullptr, nullptr, nullptr, nullptr, nullptr, nullptr,
        x, nullptr, tile_e, tile_row0, tile_rows, perm, li);
    ln_kernel<<<MTOT, 256, 0, stream>>>(x, h_hi, h_lo, ln2_g, ln2_b, eidx, perm, li);
    gemm_mfma<1, 128, 256><<<dim3(1, MAXTILE), 256, 0, stream>>>(
        h_hi, h_lo, Whi_p, Wlo_p, PK_W1, 0,
        b1, nullptr, nullptr, nullptr, nullptr, nullptr, m_hi, m_lo,
        nullptr, nullptr, tile_e, tile_row0, tile_rows, perm, li);
    gemm_mfma<3, 256, 128><<<dim3(2, MAXTILE), 256, 0, stream>>>(
        m_hi, m_lo, Whi_p, Wlo_p, PK_W2, 0,
        b2, nullptr, nullptr, out + (size_t)li * IMG, nullptr, nullptr,
        nullptr, nullptr, x, weight, tile_e, tile_row0, tile_rows, perm, li);
  }
}